// Round 12
// baseline (123.373 us; speedup 1.0000x reference)
//
#include <hip/hip_runtime.h>
#include <hip/hip_bf16.h>
#include <math.h>

#define NNODES 4096
#define MAXD 128
#define PSTR (6 * NNODES)   // part stride for es/ed partials

typedef __attribute__((ext_vector_type(8))) short bf16x8;
typedef __attribute__((ext_vector_type(4))) short bf16x4;
typedef __attribute__((ext_vector_type(4))) float f32x4;
typedef __attribute__((ext_vector_type(2))) float f32x2;
typedef __attribute__((ext_vector_type(16))) float f32x16;
typedef __attribute__((ext_vector_type(4))) ushort u16x4;

__device__ inline ushort f32_to_bf16_rne(float f) {
    uint32_t u = __float_as_uint(f);
    u += 0x7FFFu + ((u >> 16) & 1u);
    return (ushort)(u >> 16);
}
__device__ inline float bf16_to_f32(ushort h) {
    return __uint_as_float((uint32_t)h << 16);
}
__device__ inline f32x4 u4_to_f32(u16x4 v) {
    f32x4 r;
    r[0] = bf16_to_f32(v[0]); r[1] = bf16_to_f32(v[1]);
    r[2] = bf16_to_f32(v[2]); r[3] = bf16_to_f32(v[3]);
    return r;
}

// ---------------------------------------------------------------------------
// Fused prologue: [0,4096) CSR build; [4096,6976) weight transpose + x split.
// ---------------------------------------------------------------------------
__global__ __launch_bounds__(256) void pre_kern(const int* __restrict__ adj,
                                                int* __restrict__ deg,
                                                int* __restrict__ nbr,
                                                const float* __restrict__ x,
                                                const float* __restrict__ W1,
                                                const float* __restrict__ W2,
                                                const float* __restrict__ W3,
                                                ushort* __restrict__ Xhi,
                                                ushort* __restrict__ W1h,
                                                ushort* __restrict__ W2h,
                                                ushort* __restrict__ W3h) {
    __shared__ float tile[32][33];
    __shared__ int cnts[256];
    int id = blockIdx.x;
    int tid = threadIdx.x;
    if (id < 4096) {
        int n = id;
        const int* row = adj + (size_t)n * NNODES;
        int c0 = tid * 16;
        int vals[16];
        const int4* r4 = (const int4*)(row + c0);
#pragma unroll
        for (int i = 0; i < 4; i++) {
            int4 v = r4[i];
            vals[4 * i] = v.x; vals[4 * i + 1] = v.y; vals[4 * i + 2] = v.z; vals[4 * i + 3] = v.w;
        }
        int cnt = 0;
#pragma unroll
        for (int i = 0; i < 16; i++) cnt += (vals[i] != 0) ? 1 : 0;
        cnts[tid] = cnt;
        __syncthreads();
        if (tid == 0) {
            int s = 0;
            for (int i = 0; i < 256; i++) { int c = cnts[i]; cnts[i] = s; s += c; }
            deg[n] = (s < MAXD) ? s : MAXD;
        }
        __syncthreads();
        int o = cnts[tid];
        int* outr = nbr + (size_t)n * MAXD;
#pragma unroll
        for (int i = 0; i < 16; i++) {
            if (vals[i] != 0) {
                if (o < MAXD) outr[o] = c0 + i;
                o++;
            }
        }
        return;
    }
    id -= 4096;
    if (id >= 1856) {
        int i = (id - 1856) * 256 + tid;
        int k = i & 63;
        int m = i >> 6;
        float v = (k < 50) ? x[(size_t)m * 50 + k] : 0.f;
        Xhi[i] = f32_to_bf16_rne(v);
        return;
    }
    const float* W; ushort* Whi;
    int h, r, K, KP, N, NP, gy;
    if (id < 64)        { W = W1; Whi = W1h; K = 50;   KP = 64;   N = 256; NP = 256; h = id / 16;           r = id % 16;         gy = 8; }
    else if (id < 1088) { W = W2; Whi = W2h; K = 1024; KP = 1024; N = 256; NP = 256; h = (id - 64) / 256;   r = (id - 64) % 256; gy = 8; }
    else                { W = W3; Whi = W3h; K = 1024; KP = 1024; N = 121; NP = 128; h = (id - 1088) / 128; r = (id - 1088) % 128; gy = 4; }
    int k0 = (r / gy) * 32, n0 = (r % gy) * 32;
    const float* Wh_ = W + (size_t)h * K * N;
#pragma unroll
    for (int q = 0; q < 4; q++) {
        int kl = (tid >> 5) + q * 8;
        int nl = tid & 31;
        int k = k0 + kl, n = n0 + nl;
        tile[kl][nl] = (k < K && n < N) ? Wh_[(size_t)k * N + n] : 0.f;
    }
    __syncthreads();
#pragma unroll
    for (int q = 0; q < 4; q++) {
        int nl = (tid >> 5) + q * 8;
        int kl = tid & 31;
        size_t o = ((size_t)h * NP + n0 + nl) * KP + k0 + kl;
        Whi[o] = f32_to_bf16_rne(tile[kl][nl]);
    }
}

// ---------------------------------------------------------------------------
// bf16 MFMA GEMM, XCD-pinned by head. Block 128x128, 4 waves (2x2),
// wave tile 64x64 of 2x2 32x32x16 frags. BK=64, dbuf (1 barrier/step),
// register prefetch.
// LDS layout: [128 rows][64 bf16] linear (128 B rows) with bank swizzle:
//   phys(row, byte) = row*128 + (byte16 ^ ((row&7)<<4)) + (half8 ^ (((row>>3)&1)<<3))
// Frag reads are 2x ds_read_b64 (16 slots -> 4-way max, was 8-way b128).
// C written bf16; fused es/ed per-block partials from fp32 accumulators.
// ---------------------------------------------------------------------------
__global__ __launch_bounds__(256, 1) void gemm_mfma(const ushort* __restrict__ Xhi,
                                                    const ushort* __restrict__ Whi,
                                                    ushort* __restrict__ Hb,
                                                    const float* __restrict__ AsrcAll,
                                                    const float* __restrict__ AdstAll,
                                                    float* __restrict__ esp,
                                                    float* __restrict__ edp,
                                                    int KP, int NP, int Nstride, int Nreal,
                                                    int nby) {
    extern __shared__ ushort lds[];
    // ushort indices: A tile [128][64] = 8192, B tile = 8192; buffer = 16384
    constexpr int AH = 0, BH = 8192, BUF = 16384;
    int b = blockIdx.x;
    int perx = gridDim.x >> 3;
    int g = (b & 7) * perx + (b >> 3);
    int per_head = 32 * nby;
    int h = g / per_head;
    int r0 = g - h * per_head;
    const int m0 = (r0 / nby) * 128;
    const int n0 = (r0 % nby) * 128;
    const int blkj = n0 >> 7;
    const int tid = threadIdx.x;
    const int lane = tid & 63;
    const int w = tid >> 6;
    const int wr = (w >> 1) * 64, wc = (w & 1) * 64;
    const int fr = lane & 31;
    const int fg = lane >> 5;
    const ushort* Wh_ = Whi + (size_t)h * NP * KP;
    const int sr = tid >> 3;            // 0..31 (stage row base)
    const int sc8 = (tid & 7) * 8;      // 0..56 (bf16 col of 16B chunk)
    // stage-side swizzle (uniform per thread across i since 32|row steps)
    const int s_h3 = (sr >> 3) & 1;                 // (row>>3)&1
    const int s_pc = ((sc8 * 2) ^ ((sr & 7) << 4)); // physical byte col
    bf16x8 pa[4], pb[4];
    auto LOADG = [&](int K0) {
#pragma unroll
        for (int i = 0; i < 4; i++) {
            pa[i] = *(const bf16x8*)&Xhi[(size_t)(m0 + sr + 32 * i) * KP + K0 + sc8];
            pb[i] = *(const bf16x8*)&Wh_[(size_t)(n0 + sr + 32 * i) * KP + K0 + sc8];
        }
    };
    LOADG(0);
    // frag-read swizzled addresses (ushort units), constant parts
    const int f_h3 = (fr >> 3) & 1;
    const int f_x  = (fr & 7) << 3;     // ushort XOR of ((row&7)<<4) bytes
    f32x16 acc[2][2] = {};
    int cur = 0;
    for (int k0 = 0; k0 < KP; k0 += 64) {
        const int bo = cur * BUF;
#pragma unroll
        for (int i = 0; i < 4; i++) {
            int rowA = sr + 32 * i;
            bf16x8 va = pa[i], vb = pb[i];
            if (s_h3) {
                va = __builtin_shufflevector(va, va, 4, 5, 6, 7, 0, 1, 2, 3);
                vb = __builtin_shufflevector(vb, vb, 4, 5, 6, 7, 0, 1, 2, 3);
            }
            int idx = rowA * 64 + (s_pc >> 1);
            *(bf16x8*)&lds[bo + AH + idx] = va;
            *(bf16x8*)&lds[bo + BH + idx] = vb;
        }
        if (k0 + 64 < KP) LOADG(k0 + 64);
        __syncthreads();
#pragma unroll
        for (int ks = 0; ks < 4; ks++) {
            const int kc_u = ks * 16 + fg * 8;      // logical ushort col of frag
            bf16x8 ah[2], bh[2];
#pragma unroll
            for (int i = 0; i < 2; i++) {
                int row = wr + i * 32 + fr;
                int base = row * 64 + (kc_u ^ f_x);
                int lo = base + (f_h3 ? 4 : 0);
                int hi = lo ^ 4;
                bf16x4 alo = *(const bf16x4*)&lds[bo + AH + lo];
                bf16x4 ahi = *(const bf16x4*)&lds[bo + AH + hi];
                ah[i] = __builtin_shufflevector(alo, ahi, 0, 1, 2, 3, 4, 5, 6, 7);
                int rowB = wc + i * 32 + fr;
                int baseB = rowB * 64 + (kc_u ^ f_x);
                int loB = baseB + (f_h3 ? 4 : 0);
                int hiB = loB ^ 4;
                bf16x4 blo = *(const bf16x4*)&lds[bo + BH + loB];
                bf16x4 bhi = *(const bf16x4*)&lds[bo + BH + hiB];
                bh[i] = __builtin_shufflevector(blo, bhi, 0, 1, 2, 3, 4, 5, 6, 7);
            }
#pragma unroll
            for (int i = 0; i < 2; i++)
#pragma unroll
                for (int j = 0; j < 2; j++)
                    acc[i][j] = __builtin_amdgcn_mfma_f32_32x32x16_bf16(ah[i], bh[j], acc[i][j], 0, 0, 0);
        }
        cur ^= 1;
    }
    // C write (bf16): 32x32 layout col=lane&31, row=(reg&3)+8*(reg>>2)+4*(lane>>5)
#pragma unroll
    for (int i = 0; i < 2; i++)
#pragma unroll
        for (int j = 0; j < 2; j++)
#pragma unroll
            for (int reg = 0; reg < 16; reg++) {
                int row = m0 + wr + i * 32 + (reg & 3) + 8 * (reg >> 2) + 4 * fg;
                int col = n0 + wc + j * 32 + fr;
                Hb[((size_t)h * NNODES + row) * Nstride + col] = f32_to_bf16_rne(acc[i][j][reg]);
            }
    // ---- fused es/ed partials (fp32-exact from accumulators) ----
    __syncthreads();
    float* fl = (float*)lds;               // [2][128][34] es, then ed (69632 B)
    constexpr int EDO = 2 * 128 * 34;
    const float* Asrc = AsrcAll + (size_t)h * Nreal;
    const float* Adst = AdstAll + (size_t)h * Nreal;
    float as_[2], ad_[2];
#pragma unroll
    for (int j = 0; j < 2; j++) {
        int col = n0 + wc + j * 32 + fr;
        as_[j] = (col < Nreal) ? Asrc[col] : 0.f;
        ad_[j] = (col < Nreal) ? Adst[col] : 0.f;
    }
    const int wcidx = (w & 1);
#pragma unroll
    for (int i = 0; i < 2; i++)
#pragma unroll
        for (int reg = 0; reg < 16; reg++) {
            int row = wr + i * 32 + (reg & 3) + 8 * (reg >> 2) + 4 * fg;
            float pe = acc[i][0][reg] * as_[0] + acc[i][1][reg] * as_[1];
            float pd = acc[i][0][reg] * ad_[0] + acc[i][1][reg] * ad_[1];
            fl[(wcidx * 128 + row) * 34 + fr] = pe;
            fl[EDO + (wcidx * 128 + row) * 34 + fr] = pd;
        }
    __syncthreads();
    if (tid < 128) {
        int r = tid;
        float s = 0.f;
#pragma unroll
        for (int q = 0; q < 32; q++)
            s += fl[r * 34 + q] + fl[(128 + r) * 34 + q];
        esp[(size_t)blkj * PSTR + h * NNODES + m0 + r] = s;
    } else {
        int r = tid - 128;
        float s = 0.f;
#pragma unroll
        for (int q = 0; q < 32; q++)
            s += fl[EDO + r * 34 + q] + fl[EDO + (128 + r) * 34 + q];
        edp[(size_t)blkj * PSTR + h * NNODES + m0 + r] = s;
    }
}

// ---------------------------------------------------------------------------
// Sparse masked-softmax attention aggregate, layers 1/2 (FOUT=256, bf16 Hb).
// XCD-pinned by head. 4-way unrolled gathers, 4 independent accumulators.
// ---------------------------------------------------------------------------
template<int HEADS, int NPARTS, bool RES>
__global__ __launch_bounds__(256) void aggregate_kern(const ushort* __restrict__ Hb,
                                                      const float* __restrict__ esp,
                                                      const float* __restrict__ edp,
                                                      const int* __restrict__ deg,
                                                      const int* __restrict__ nbr,
                                                      ushort* outHi) {
    constexpr int FOUT = 256;
    int b = blockIdx.x;
    int g = (b & 7) * ((HEADS * NNODES / 4) / 8) + (b >> 3);
    int h = g / (NNODES / 4);
    int n = (g % (NNODES / 4)) * 4 + (threadIdx.x >> 6);
    int lane = threadIdx.x & 63;
    int d = deg[n];
    const int* nb = nbr + (size_t)n * MAXD;
    float esn = esp[h * NNODES + n];
    if (NPARTS == 2) esn += esp[PSTR + h * NNODES + n];
    float sc[2];
    int nm[2];
    float mx = -INFINITY;
#pragma unroll
    for (int r = 0; r < 2; r++) {
        int j = lane + r * 64;
        int m = (j < d) ? nb[j] : 0;
        nm[r] = m;
        float e = -INFINITY;
        if (j < d) {
            float t = esn + edp[h * NNODES + m];
            if (NPARTS == 2) t += edp[PSTR + h * NNODES + m];
            e = (t > 0.f) ? t : 0.2f * t;
        }
        sc[r] = e;
        mx = fmaxf(mx, e);
    }
#pragma unroll
    for (int sh = 32; sh >= 1; sh >>= 1) mx = fmaxf(mx, __shfl_xor(mx, sh));
    float sum = 0.f;
#pragma unroll
    for (int r = 0; r < 2; r++) {
        float ex = (sc[r] == -INFINITY) ? 0.f : expf(sc[r] - mx);
        sc[r] = ex;
        sum += ex;
    }
#pragma unroll
    for (int sh = 32; sh >= 1; sh >>= 1) sum += __shfl_xor(sum, sh);
    float inv = 1.f / sum;
    sc[0] *= inv; sc[1] *= inv;
    const ushort* Hh = Hb + (size_t)h * NNODES * FOUT;
    f32x4 ac0 = {}, ac1 = {}, ac2 = {}, ac3 = {};
    int j = 0;
    for (; j + 3 < d; j += 4) {
        float a0 = __shfl(sc[j >> 6], j & 63);
        int q0 = __shfl(nm[j >> 6], j & 63);
        float a1 = __shfl(sc[(j + 1) >> 6], (j + 1) & 63);
        int q1 = __shfl(nm[(j + 1) >> 6], (j + 1) & 63);
        float a2 = __shfl(sc[(j + 2) >> 6], (j + 2) & 63);
        int q2 = __shfl(nm[(j + 2) >> 6], (j + 2) & 63);
        float a3 = __shfl(sc[(j + 3) >> 6], (j + 3) & 63);
        int q3 = __shfl(nm[(j + 3) >> 6], (j + 3) & 63);
        u16x4 v0 = *(const u16x4*)&Hh[(size_t)q0 * FOUT + lane * 4];
        u16x4 v1 = *(const u16x4*)&Hh[(size_t)q1 * FOUT + lane * 4];
        u16x4 v2 = *(const u16x4*)&Hh[(size_t)q2 * FOUT + lane * 4];
        u16x4 v3 = *(const u16x4*)&Hh[(size_t)q3 * FOUT + lane * 4];
        ac0 += a0 * u4_to_f32(v0);
        ac1 += a1 * u4_to_f32(v1);
        ac2 += a2 * u4_to_f32(v2);
        ac3 += a3 * u4_to_f32(v3);
    }
    for (; j < d; j++) {
        float a0 = __shfl(sc[j >> 6], j & 63);
        int q0 = __shfl(nm[j >> 6], j & 63);
        u16x4 v0 = *(const u16x4*)&Hh[(size_t)q0 * FOUT + lane * 4];
        ac0 += a0 * u4_to_f32(v0);
    }
    f32x4 acc = (ac0 + ac1) + (ac2 + ac3);
    size_t idx = (size_t)n * (HEADS * FOUT) + (size_t)h * FOUT + lane * 4;
    u16x4 hi4, rh;
    if (RES) rh = *(const u16x4*)&outHi[idx];
#pragma unroll
    for (int i = 0; i < 4; i++) {
        float v = acc[i];
        v = (v > 0.f) ? v : (expf(v) - 1.f);
        if (RES) v += bf16_to_f32(rh[i]);
        hi4[i] = f32_to_bf16_rne(v);
    }
    *(u16x4*)&outHi[idx] = hi4;
}

// ---------------------------------------------------------------------------
// Layer 3a: per-(h,n) pinned aggregate -> agg[h][n][128] (fp32, stride 128).
// ---------------------------------------------------------------------------
__global__ __launch_bounds__(256) void aggregate3a_kern(const ushort* __restrict__ Hb,
                                                        const float* __restrict__ esp,
                                                        const float* __restrict__ edp,
                                                        const int* __restrict__ deg,
                                                        const int* __restrict__ nbr,
                                                        float* __restrict__ agg) {
    constexpr int HEADS = 6;
    int b = blockIdx.x;
    int g = (b & 7) * ((HEADS * NNODES / 4) / 8) + (b >> 3);
    int h = g / (NNODES / 4);
    int n = (g % (NNODES / 4)) * 4 + (threadIdx.x >> 6);
    int lane = threadIdx.x & 63;
    int d = deg[n];
    const int* nb = nbr + (size_t)n * MAXD;
    float esn = esp[h * NNODES + n];
    float sc[2];
    int nm[2];
    float mx = -INFINITY;
#pragma unroll
    for (int r = 0; r < 2; r++) {
        int j = lane + r * 64;
        int m = (j < d) ? nb[j] : 0;
        nm[r] = m;
        float e = -INFINITY;
        if (j < d) {
            float t = esn + edp[h * NNODES + m];
            e = (t > 0.f) ? t : 0.2f * t;
        }
        sc[r] = e;
        mx = fmaxf(mx, e);
    }
#pragma unroll
    for (int sh = 32; sh >= 1; sh >>= 1) mx = fmaxf(mx, __shfl_xor(mx, sh));
    float sum = 0.f;
#pragma unroll
    for (int r = 0; r < 2; r++) {
        float ex = (sc[r] == -INFINITY) ? 0.f : expf(sc[r] - mx);
        sc[r] = ex;
        sum += ex;
    }
#pragma unroll
    for (int sh = 32; sh >= 1; sh >>= 1) sum += __shfl_xor(sum, sh);
    float inv = 1.f / sum;
    sc[0] *= inv; sc[1] *= inv;
    const ushort* Hh = Hb + (size_t)h * NNODES * 128;
    int c0 = lane * 2;
    f32x2 ac0 = {}, ac1 = {}, ac2 = {}, ac3 = {};
    auto LD = [&](int q) -> f32x2 {
        uint vv = *(const uint*)&Hh[(size_t)q * 128 + c0];
        f32x2 r;
        r[0] = bf16_to_f32((ushort)(vv & 0xffffu));
        r[1] = bf16_to_f32((ushort)(vv >> 16));
        return r;
    };
    int j = 0;
    for (; j + 3 < d; j += 4) {
        float a0 = __shfl(sc[j >> 6], j & 63);
        int q0 = __shfl(nm[j >> 6], j & 63);
        float a1 = __shfl(sc[(j + 1) >> 6], (j + 1) & 63);
        int q1 = __shfl(nm[(j + 1) >> 6], (j + 1) & 63);
        float a2 = __shfl(sc[(j + 2) >> 6], (j + 2) & 63);
        int q2 = __shfl(nm[(j + 2) >> 6], (j + 2) & 63);
        float a3 = __shfl(sc[(j + 3) >> 6], (j + 3) & 63);
        int q3 = __shfl(nm[(j + 3) >> 6], (j + 3) & 63);
        ac0 += a0 * LD(q0);
        ac1 += a1 * LD(q1);
        ac2 += a2 * LD(q2);
        ac3 += a3 * LD(q3);
    }
    for (; j < d; j++) {
        float a0 = __shfl(sc[j >> 6], j & 63);
        int q0 = __shfl(nm[j >> 6], j & 63);
        ac0 += a0 * LD(q0);
    }
    f32x2 acc = (ac0 + ac1) + (ac2 + ac3);
    *(f32x2*)&agg[((size_t)h * NNODES + n) * 128 + c0] = acc;
}

// ---------------------------------------------------------------------------
// Layer 3b: mean over 6 heads + row log_softmax (121 classes). 1 wave/node.
// ---------------------------------------------------------------------------
__global__ __launch_bounds__(256) void reduce3_kern(const float* __restrict__ agg,
                                                    float* __restrict__ outp) {
    constexpr int FOUT = 121;
    int n = blockIdx.x * 4 + (threadIdx.x >> 6);
    int lane = threadIdx.x & 63;
    int c0 = lane * 2;
    f32x2 l = {};
#pragma unroll
    for (int h = 0; h < 6; h++)
        l += *(const f32x2*)&agg[((size_t)h * NNODES + n) * 128 + c0];
    l = l * (1.f / 6.f);
    float m0 = (c0 < FOUT) ? l[0] : -INFINITY;
    float m1 = (c0 + 1 < FOUT) ? l[1] : -INFINITY;
    float mx = fmaxf(m0, m1);
#pragma unroll
    for (int sh = 32; sh >= 1; sh >>= 1) mx = fmaxf(mx, __shfl_xor(mx, sh));
    float s = ((c0 < FOUT) ? expf(l[0] - mx) : 0.f) + ((c0 + 1 < FOUT) ? expf(l[1] - mx) : 0.f);
#pragma unroll
    for (int sh = 32; sh >= 1; sh >>= 1) s += __shfl_xor(s, sh);
    float lse = logf(s);
    if (c0 < FOUT) outp[(size_t)n * FOUT + c0] = l[0] - mx - lse;
    if (c0 + 1 < FOUT) outp[(size_t)n * FOUT + c0 + 1] = l[1] - mx - lse;
}

// ---------------------------------------------------------------------------
extern "C" void kernel_launch(void* const* d_in, const int* in_sizes, int n_in,
                              void* d_out, int out_size, void* d_ws, size_t ws_size,
                              hipStream_t stream) {
    const float* x   = (const float*)d_in[0];
    const int*   adj = (const int*)d_in[1];
    const float* W1  = (const float*)d_in[2];
    const float* a1s = (const float*)d_in[3];
    const float* a1d = (const float*)d_in[4];
    const float* W2  = (const float*)d_in[5];
    const float* a2s = (const float*)d_in[6];
    const float* a2d = (const float*)d_in[7];
    const float* W3  = (const float*)d_in[8];
    const float* a3s = (const float*)d_in[9];
    const float* a3d = (const float*)d_in[10];
    float* outp = (float*)d_out;

    char* w = (char*)d_ws;
    int* deg = (int*)w;      w += (size_t)NNODES * sizeof(int);
    int* nbr = (int*)w;      w += (size_t)NNODES * MAXD * sizeof(int);
    ushort* hbuf = (ushort*)w; w += (size_t)4 * NNODES * 256 * sizeof(ushort); // 8 MB bf16
    float* esp = (float*)w;  w += (size_t)2 * PSTR * sizeof(float);
    float* edp = (float*)w;  w += (size_t)2 * PSTR * sizeof(float);
    ushort* Xhi = (ushort*)w; w += (size_t)NNODES * 1024 * sizeof(ushort);   // shared for x/x1/x2
    ushort* W1h = (ushort*)w; w += (size_t)4 * 256 * 64 * sizeof(ushort);
    ushort* W2h = (ushort*)w; w += (size_t)4 * 256 * 1024 * sizeof(ushort);
    ushort* W3h = (ushort*)w; w += (size_t)6 * 128 * 1024 * sizeof(ushort);
    float* agg = (float*)w;  w += (size_t)6 * NNODES * 128 * sizeof(float);  // 12.6 MB

    // LDS: tiles need 64 KB (2 buf x 32 KB); es/ed epilogue needs 69632 B -> 72 KB
    constexpr size_t GEMM_LDS = 73728;

    // ---- fused CSR + weight/x prep (4096 + 2880 blocks)
    pre_kern<<<6976, 256, 0, stream>>>(adj, deg, nbr, x, W1, W2, W3,
                                       Xhi, W1h, W2h, W3h);

    // ---- Layer 1: x[4096,50] -> x1 (bf16 in Xhi)
    gemm_mfma<<<256, 256, GEMM_LDS, stream>>>(Xhi, W1h, hbuf,
                                              a1s, a1d, esp, edp, 64, 256, 256, 256, 2);
    aggregate_kern<4, 2, false><<<4 * NNODES / 4, 256, 0, stream>>>(
        hbuf, esp, edp, deg, nbr, Xhi);

    // ---- Layer 2: x1 -> x2 = ELU(gat(x1)) + x1 (residual from bf16 x1)
    gemm_mfma<<<256, 256, GEMM_LDS, stream>>>(Xhi, W2h, hbuf,
                                              a2s, a2d, esp, edp, 1024, 256, 256, 256, 2);
    aggregate_kern<4, 2, true><<<4 * NNODES / 4, 256, 0, stream>>>(
        hbuf, esp, edp, deg, nbr, Xhi);

    // ---- Layer 3: x2 -> out = log_softmax(mean_h gat(x2)); Hb bf16 stride 128
    gemm_mfma<<<192, 256, GEMM_LDS, stream>>>(Xhi, W3h, hbuf,
                                              a3s, a3d, esp, edp, 1024, 128, 128, 121, 1);
    aggregate3a_kern<<<6 * NNODES / 4, 256, 0, stream>>>(hbuf, esp, edp, deg, nbr, agg);
    reduce3_kern<<<NNODES / 4, 256, 0, stream>>>(agg, outp);
}

// Round 13
// 121.729 us; speedup vs baseline: 1.0135x; 1.0135x over previous
//
#include <hip/hip_runtime.h>
#include <hip/hip_bf16.h>
#include <math.h>

#define NNODES 4096
#define MAXD 128
#define PSTR (6 * NNODES)   // part stride for es/ed partials

typedef __attribute__((ext_vector_type(8))) short bf16x8;
typedef __attribute__((ext_vector_type(4))) float f32x4;
typedef __attribute__((ext_vector_type(2))) float f32x2;
typedef __attribute__((ext_vector_type(16))) float f32x16;
typedef __attribute__((ext_vector_type(4))) ushort u16x4;

__device__ inline ushort f32_to_bf16_rne(float f) {
    uint32_t u = __float_as_uint(f);
    u += 0x7FFFu + ((u >> 16) & 1u);
    return (ushort)(u >> 16);
}
__device__ inline float bf16_to_f32(ushort h) {
    return __uint_as_float((uint32_t)h << 16);
}
__device__ inline f32x4 u4_to_f32(u16x4 v) {
    f32x4 r;
    r[0] = bf16_to_f32(v[0]); r[1] = bf16_to_f32(v[1]);
    r[2] = bf16_to_f32(v[2]); r[3] = bf16_to_f32(v[3]);
    return r;
}

// ---------------------------------------------------------------------------
// Fused prologue: [0,4096) CSR build; [4096,6976) weight transpose + x split.
// ---------------------------------------------------------------------------
__global__ __launch_bounds__(256) void pre_kern(const int* __restrict__ adj,
                                                int* __restrict__ deg,
                                                int* __restrict__ nbr,
                                                const float* __restrict__ x,
                                                const float* __restrict__ W1,
                                                const float* __restrict__ W2,
                                                const float* __restrict__ W3,
                                                ushort* __restrict__ Xhi,
                                                ushort* __restrict__ W1h,
                                                ushort* __restrict__ W2h,
                                                ushort* __restrict__ W3h) {
    __shared__ float tile[32][33];
    __shared__ int cnts[256];
    int id = blockIdx.x;
    int tid = threadIdx.x;
    if (id < 4096) {
        int n = id;
        const int* row = adj + (size_t)n * NNODES;
        int c0 = tid * 16;
        int vals[16];
        const int4* r4 = (const int4*)(row + c0);
#pragma unroll
        for (int i = 0; i < 4; i++) {
            int4 v = r4[i];
            vals[4 * i] = v.x; vals[4 * i + 1] = v.y; vals[4 * i + 2] = v.z; vals[4 * i + 3] = v.w;
        }
        int cnt = 0;
#pragma unroll
        for (int i = 0; i < 16; i++) cnt += (vals[i] != 0) ? 1 : 0;
        cnts[tid] = cnt;
        __syncthreads();
        if (tid == 0) {
            int s = 0;
            for (int i = 0; i < 256; i++) { int c = cnts[i]; cnts[i] = s; s += c; }
            deg[n] = (s < MAXD) ? s : MAXD;
        }
        __syncthreads();
        int o = cnts[tid];
        int* outr = nbr + (size_t)n * MAXD;
#pragma unroll
        for (int i = 0; i < 16; i++) {
            if (vals[i] != 0) {
                if (o < MAXD) outr[o] = c0 + i;
                o++;
            }
        }
        return;
    }
    id -= 4096;
    if (id >= 1856) {
        int i = (id - 1856) * 256 + tid;
        int k = i & 63;
        int m = i >> 6;
        float v = (k < 50) ? x[(size_t)m * 50 + k] : 0.f;
        Xhi[i] = f32_to_bf16_rne(v);
        return;
    }
    const float* W; ushort* Whi;
    int h, r, K, KP, N, NP, gy;
    if (id < 64)        { W = W1; Whi = W1h; K = 50;   KP = 64;   N = 256; NP = 256; h = id / 16;           r = id % 16;         gy = 8; }
    else if (id < 1088) { W = W2; Whi = W2h; K = 1024; KP = 1024; N = 256; NP = 256; h = (id - 64) / 256;   r = (id - 64) % 256; gy = 8; }
    else                { W = W3; Whi = W3h; K = 1024; KP = 1024; N = 121; NP = 128; h = (id - 1088) / 128; r = (id - 1088) % 128; gy = 4; }
    int k0 = (r / gy) * 32, n0 = (r % gy) * 32;
    const float* Wh_ = W + (size_t)h * K * N;
#pragma unroll
    for (int q = 0; q < 4; q++) {
        int kl = (tid >> 5) + q * 8;
        int nl = tid & 31;
        int k = k0 + kl, n = n0 + nl;
        tile[kl][nl] = (k < K && n < N) ? Wh_[(size_t)k * N + n] : 0.f;
    }
    __syncthreads();
#pragma unroll
    for (int q = 0; q < 4; q++) {
        int nl = (tid >> 5) + q * 8;
        int kl = tid & 31;
        size_t o = ((size_t)h * NP + n0 + nl) * KP + k0 + kl;
        Whi[o] = f32_to_bf16_rne(tile[kl][nl]);
    }
}

// ---------------------------------------------------------------------------
// bf16 MFMA GEMM, XCD-pinned by head. Block 128x128, 4 waves (2x2),
// wave tile 64x64 of 2x2 32x32x16 frags. BK=64.
// Staging: __builtin_amdgcn_global_load_lds width=16, double-buffered,
// issue-next-before-compute, ONE barrier/step (T3-minimum schedule).
// LDS linear [128][64] bf16 with source-side chunk swizzle lc = pc^(row&7);
// frag b128 reads apply the same involution -> conflict-free (8-cy floor).
// C written bf16; fused es/ed per-block partials from fp32 accumulators.
// ---------------------------------------------------------------------------
__global__ __launch_bounds__(256, 1) void gemm_mfma(const ushort* __restrict__ Xhi,
                                                    const ushort* __restrict__ Whi,
                                                    ushort* __restrict__ Hb,
                                                    const float* __restrict__ AsrcAll,
                                                    const float* __restrict__ AdstAll,
                                                    float* __restrict__ esp,
                                                    float* __restrict__ edp,
                                                    int KP, int NP, int Nstride, int Nreal,
                                                    int nby) {
    extern __shared__ ushort lds[];
    constexpr int AH = 0, BH = 8192, BUF = 16384;   // ushort idx; tile 128x64
    int b = blockIdx.x;
    int perx = gridDim.x >> 3;
    int g = (b & 7) * perx + (b >> 3);
    int per_head = 32 * nby;
    int h = g / per_head;
    int r0 = g - h * per_head;
    const int m0 = (r0 / nby) * 128;
    const int n0 = (r0 % nby) * 128;
    const int blkj = n0 >> 7;
    const int tid = threadIdx.x;
    const int lane = tid & 63;
    const int w = tid >> 6;
    const int wr = (w >> 1) * 64, wc = (w & 1) * 64;
    const int fr = lane & 31;
    const int fg = lane >> 5;
    const ushort* Wh_ = Whi + (size_t)h * NP * KP;
    // staging: chunk c = w*64 + i*256 + lane; row=c>>3, pc=c&7, lc=pc^(row&7)
    auto STAGE = [&](int buf, int K0) {
#pragma unroll
        for (int i = 0; i < 4; i++) {
            int c = w * 64 + i * 256 + lane;
            int row = c >> 3;
            int lc = (c & 7) ^ (row & 7);
            const ushort* ga = &Xhi[(size_t)(m0 + row) * KP + K0 + lc * 8];
            const ushort* gb = &Wh_[(size_t)(n0 + row) * KP + K0 + lc * 8];
            ushort* la = &lds[buf * BUF + AH + (w * 64 + i * 256) * 8];
            ushort* lb = &lds[buf * BUF + BH + (w * 64 + i * 256) * 8];
            __builtin_amdgcn_global_load_lds(
                (const __attribute__((address_space(1))) uint32_t*)ga,
                (__attribute__((address_space(3))) uint32_t*)la, 16, 0, 0);
            __builtin_amdgcn_global_load_lds(
                (const __attribute__((address_space(1))) uint32_t*)gb,
                (__attribute__((address_space(3))) uint32_t*)lb, 16, 0, 0);
        }
    };
    STAGE(0, 0);
    __syncthreads();
    f32x16 acc[2][2] = {};
    int cur = 0;
    for (int k0 = 0; k0 < KP; k0 += 64) {
        if (k0 + 64 < KP) STAGE(cur ^ 1, k0 + 64);   // async, lands before next barrier
        const int bo = cur * BUF;
#pragma unroll
        for (int ks = 0; ks < 4; ks++) {
            const int pc = (ks * 2 + fg) ^ (fr & 7);
            bf16x8 ah[2], bh[2];
#pragma unroll
            for (int i = 0; i < 2; i++) {
                int rowA = wr + i * 32 + fr;
                ah[i] = *(const bf16x8*)&lds[bo + AH + rowA * 64 + pc * 8];
                int rowB = wc + i * 32 + fr;
                bh[i] = *(const bf16x8*)&lds[bo + BH + rowB * 64 + pc * 8];
            }
#pragma unroll
            for (int i = 0; i < 2; i++)
#pragma unroll
                for (int j = 0; j < 2; j++)
                    acc[i][j] = __builtin_amdgcn_mfma_f32_32x32x16_bf16(ah[i], bh[j], acc[i][j], 0, 0, 0);
        }
        __syncthreads();    // waves done with buf[cur]; drains next-tile loads
        cur ^= 1;
    }
    // C write (bf16): 32x32 layout col=lane&31, row=(reg&3)+8*(reg>>2)+4*(lane>>5)
#pragma unroll
    for (int i = 0; i < 2; i++)
#pragma unroll
        for (int j = 0; j < 2; j++)
#pragma unroll
            for (int reg = 0; reg < 16; reg++) {
                int row = m0 + wr + i * 32 + (reg & 3) + 8 * (reg >> 2) + 4 * fg;
                int col = n0 + wc + j * 32 + fr;
                Hb[((size_t)h * NNODES + row) * Nstride + col] = f32_to_bf16_rne(acc[i][j][reg]);
            }
    // ---- fused es/ed partials (fp32-exact from accumulators) ----
    __syncthreads();
    float* fl = (float*)lds;               // [2][128][34] es, then ed (69632 B)
    constexpr int EDO = 2 * 128 * 34;
    const float* Asrc = AsrcAll + (size_t)h * Nreal;
    const float* Adst = AdstAll + (size_t)h * Nreal;
    float as_[2], ad_[2];
#pragma unroll
    for (int j = 0; j < 2; j++) {
        int col = n0 + wc + j * 32 + fr;
        as_[j] = (col < Nreal) ? Asrc[col] : 0.f;
        ad_[j] = (col < Nreal) ? Adst[col] : 0.f;
    }
    const int wcidx = (w & 1);
#pragma unroll
    for (int i = 0; i < 2; i++)
#pragma unroll
        for (int reg = 0; reg < 16; reg++) {
            int row = wr + i * 32 + (reg & 3) + 8 * (reg >> 2) + 4 * fg;
            float pe = acc[i][0][reg] * as_[0] + acc[i][1][reg] * as_[1];
            float pd = acc[i][0][reg] * ad_[0] + acc[i][1][reg] * ad_[1];
            fl[(wcidx * 128 + row) * 34 + fr] = pe;
            fl[EDO + (wcidx * 128 + row) * 34 + fr] = pd;
        }
    __syncthreads();
    if (tid < 128) {
        int r = tid;
        float s = 0.f;
#pragma unroll
        for (int q = 0; q < 32; q++)
            s += fl[r * 34 + q] + fl[(128 + r) * 34 + q];
        esp[(size_t)blkj * PSTR + h * NNODES + m0 + r] = s;
    } else {
        int r = tid - 128;
        float s = 0.f;
#pragma unroll
        for (int q = 0; q < 32; q++)
            s += fl[EDO + r * 34 + q] + fl[EDO + (128 + r) * 34 + q];
        edp[(size_t)blkj * PSTR + h * NNODES + m0 + r] = s;
    }
}

// ---------------------------------------------------------------------------
// Sparse masked-softmax attention aggregate, layers 1/2 (FOUT=256, bf16 Hb).
// XCD-pinned by head. 4-way unrolled gathers, 4 independent accumulators.
// ---------------------------------------------------------------------------
template<int HEADS, int NPARTS, bool RES>
__global__ __launch_bounds__(256) void aggregate_kern(const ushort* __restrict__ Hb,
                                                      const float* __restrict__ esp,
                                                      const float* __restrict__ edp,
                                                      const int* __restrict__ deg,
                                                      const int* __restrict__ nbr,
                                                      ushort* outHi) {
    constexpr int FOUT = 256;
    int b = blockIdx.x;
    int g = (b & 7) * ((HEADS * NNODES / 4) / 8) + (b >> 3);
    int h = g / (NNODES / 4);
    int n = (g % (NNODES / 4)) * 4 + (threadIdx.x >> 6);
    int lane = threadIdx.x & 63;
    int d = deg[n];
    const int* nb = nbr + (size_t)n * MAXD;
    float esn = esp[h * NNODES + n];
    if (NPARTS == 2) esn += esp[PSTR + h * NNODES + n];
    float sc[2];
    int nm[2];
    float mx = -INFINITY;
#pragma unroll
    for (int r = 0; r < 2; r++) {
        int j = lane + r * 64;
        int m = (j < d) ? nb[j] : 0;
        nm[r] = m;
        float e = -INFINITY;
        if (j < d) {
            float t = esn + edp[h * NNODES + m];
            if (NPARTS == 2) t += edp[PSTR + h * NNODES + m];
            e = (t > 0.f) ? t : 0.2f * t;
        }
        sc[r] = e;
        mx = fmaxf(mx, e);
    }
#pragma unroll
    for (int sh = 32; sh >= 1; sh >>= 1) mx = fmaxf(mx, __shfl_xor(mx, sh));
    float sum = 0.f;
#pragma unroll
    for (int r = 0; r < 2; r++) {
        float ex = (sc[r] == -INFINITY) ? 0.f : expf(sc[r] - mx);
        sc[r] = ex;
        sum += ex;
    }
#pragma unroll
    for (int sh = 32; sh >= 1; sh >>= 1) sum += __shfl_xor(sum, sh);
    float inv = 1.f / sum;
    sc[0] *= inv; sc[1] *= inv;
    const ushort* Hh = Hb + (size_t)h * NNODES * FOUT;
    f32x4 ac0 = {}, ac1 = {}, ac2 = {}, ac3 = {};
    int j = 0;
    for (; j + 3 < d; j += 4) {
        float a0 = __shfl(sc[j >> 6], j & 63);
        int q0 = __shfl(nm[j >> 6], j & 63);
        float a1 = __shfl(sc[(j + 1) >> 6], (j + 1) & 63);
        int q1 = __shfl(nm[(j + 1) >> 6], (j + 1) & 63);
        float a2 = __shfl(sc[(j + 2) >> 6], (j + 2) & 63);
        int q2 = __shfl(nm[(j + 2) >> 6], (j + 2) & 63);
        float a3 = __shfl(sc[(j + 3) >> 6], (j + 3) & 63);
        int q3 = __shfl(nm[(j + 3) >> 6], (j + 3) & 63);
        u16x4 v0 = *(const u16x4*)&Hh[(size_t)q0 * FOUT + lane * 4];
        u16x4 v1 = *(const u16x4*)&Hh[(size_t)q1 * FOUT + lane * 4];
        u16x4 v2 = *(const u16x4*)&Hh[(size_t)q2 * FOUT + lane * 4];
        u16x4 v3 = *(const u16x4*)&Hh[(size_t)q3 * FOUT + lane * 4];
        ac0 += a0 * u4_to_f32(v0);
        ac1 += a1 * u4_to_f32(v1);
        ac2 += a2 * u4_to_f32(v2);
        ac3 += a3 * u4_to_f32(v3);
    }
    for (; j < d; j++) {
        float a0 = __shfl(sc[j >> 6], j & 63);
        int q0 = __shfl(nm[j >> 6], j & 63);
        u16x4 v0 = *(const u16x4*)&Hh[(size_t)q0 * FOUT + lane * 4];
        ac0 += a0 * u4_to_f32(v0);
    }
    f32x4 acc = (ac0 + ac1) + (ac2 + ac3);
    size_t idx = (size_t)n * (HEADS * FOUT) + (size_t)h * FOUT + lane * 4;
    u16x4 hi4, rh;
    if (RES) rh = *(const u16x4*)&outHi[idx];
#pragma unroll
    for (int i = 0; i < 4; i++) {
        float v = acc[i];
        v = (v > 0.f) ? v : (expf(v) - 1.f);
        if (RES) v += bf16_to_f32(rh[i]);
        hi4[i] = f32_to_bf16_rne(v);
    }
    *(u16x4*)&outHi[idx] = hi4;
}

// ---------------------------------------------------------------------------
// Layer 3a: per-(h,n) pinned aggregate -> agg[h][n][128] (fp32, stride 128).
// ---------------------------------------------------------------------------
__global__ __launch_bounds__(256) void aggregate3a_kern(const ushort* __restrict__ Hb,
                                                        const float* __restrict__ esp,
                                                        const float* __restrict__ edp,
                                                        const int* __restrict__ deg,
                                                        const int* __restrict__ nbr,
                                                        float* __restrict__ agg) {
    constexpr int HEADS = 6;
    int b = blockIdx.x;
    int g = (b & 7) * ((HEADS * NNODES / 4) / 8) + (b >> 3);
    int h = g / (NNODES / 4);
    int n = (g % (NNODES / 4)) * 4 + (threadIdx.x >> 6);
    int lane = threadIdx.x & 63;
    int d = deg[n];
    const int* nb = nbr + (size_t)n * MAXD;
    float esn = esp[h * NNODES + n];
    float sc[2];
    int nm[2];
    float mx = -INFINITY;
#pragma unroll
    for (int r = 0; r < 2; r++) {
        int j = lane + r * 64;
        int m = (j < d) ? nb[j] : 0;
        nm[r] = m;
        float e = -INFINITY;
        if (j < d) {
            float t = esn + edp[h * NNODES + m];
            e = (t > 0.f) ? t : 0.2f * t;
        }
        sc[r] = e;
        mx = fmaxf(mx, e);
    }
#pragma unroll
    for (int sh = 32; sh >= 1; sh >>= 1) mx = fmaxf(mx, __shfl_xor(mx, sh));
    float sum = 0.f;
#pragma unroll
    for (int r = 0; r < 2; r++) {
        float ex = (sc[r] == -INFINITY) ? 0.f : expf(sc[r] - mx);
        sc[r] = ex;
        sum += ex;
    }
#pragma unroll
    for (int sh = 32; sh >= 1; sh >>= 1) sum += __shfl_xor(sum, sh);
    float inv = 1.f / sum;
    sc[0] *= inv; sc[1] *= inv;
    const ushort* Hh = Hb + (size_t)h * NNODES * 128;
    int c0 = lane * 2;
    f32x2 ac0 = {}, ac1 = {}, ac2 = {}, ac3 = {};
    auto LD = [&](int q) -> f32x2 {
        uint vv = *(const uint*)&Hh[(size_t)q * 128 + c0];
        f32x2 r;
        r[0] = bf16_to_f32((ushort)(vv & 0xffffu));
        r[1] = bf16_to_f32((ushort)(vv >> 16));
        return r;
    };
    int j = 0;
    for (; j + 3 < d; j += 4) {
        float a0 = __shfl(sc[j >> 6], j & 63);
        int q0 = __shfl(nm[j >> 6], j & 63);
        float a1 = __shfl(sc[(j + 1) >> 6], (j + 1) & 63);
        int q1 = __shfl(nm[(j + 1) >> 6], (j + 1) & 63);
        float a2 = __shfl(sc[(j + 2) >> 6], (j + 2) & 63);
        int q2 = __shfl(nm[(j + 2) >> 6], (j + 2) & 63);
        float a3 = __shfl(sc[(j + 3) >> 6], (j + 3) & 63);
        int q3 = __shfl(nm[(j + 3) >> 6], (j + 3) & 63);
        ac0 += a0 * LD(q0);
        ac1 += a1 * LD(q1);
        ac2 += a2 * LD(q2);
        ac3 += a3 * LD(q3);
    }
    for (; j < d; j++) {
        float a0 = __shfl(sc[j >> 6], j & 63);
        int q0 = __shfl(nm[j >> 6], j & 63);
        ac0 += a0 * LD(q0);
    }
    f32x2 acc = (ac0 + ac1) + (ac2 + ac3);
    *(f32x2*)&agg[((size_t)h * NNODES + n) * 128 + c0] = acc;
}

// ---------------------------------------------------------------------------
// Layer 3b: mean over 6 heads + row log_softmax (121 classes). 1 wave/node.
// ---------------------------------------------------------------------------
__global__ __launch_bounds__(256) void reduce3_kern(const float* __restrict__ agg,
                                                    float* __restrict__ outp) {
    constexpr int FOUT = 121;
    int n = blockIdx.x * 4 + (threadIdx.x >> 6);
    int lane = threadIdx.x & 63;
    int c0 = lane * 2;
    f32x2 l = {};
#pragma unroll
    for (int h = 0; h < 6; h++)
        l += *(const f32x2*)&agg[((size_t)h * NNODES + n) * 128 + c0];
    l = l * (1.f / 6.f);
    float m0 = (c0 < FOUT) ? l[0] : -INFINITY;
    float m1 = (c0 + 1 < FOUT) ? l[1] : -INFINITY;
    float mx = fmaxf(m0, m1);
#pragma unroll
    for (int sh = 32; sh >= 1; sh >>= 1) mx = fmaxf(mx, __shfl_xor(mx, sh));
    float s = ((c0 < FOUT) ? expf(l[0] - mx) : 0.f) + ((c0 + 1 < FOUT) ? expf(l[1] - mx) : 0.f);
#pragma unroll
    for (int sh = 32; sh >= 1; sh >>= 1) s += __shfl_xor(s, sh);
    float lse = logf(s);
    if (c0 < FOUT) outp[(size_t)n * FOUT + c0] = l[0] - mx - lse;
    if (c0 + 1 < FOUT) outp[(size_t)n * FOUT + c0 + 1] = l[1] - mx - lse;
}

// ---------------------------------------------------------------------------
extern "C" void kernel_launch(void* const* d_in, const int* in_sizes, int n_in,
                              void* d_out, int out_size, void* d_ws, size_t ws_size,
                              hipStream_t stream) {
    const float* x   = (const float*)d_in[0];
    const int*   adj = (const int*)d_in[1];
    const float* W1  = (const float*)d_in[2];
    const float* a1s = (const float*)d_in[3];
    const float* a1d = (const float*)d_in[4];
    const float* W2  = (const float*)d_in[5];
    const float* a2s = (const float*)d_in[6];
    const float* a2d = (const float*)d_in[7];
    const float* W3  = (const float*)d_in[8];
    const float* a3s = (const float*)d_in[9];
    const float* a3d = (const float*)d_in[10];
    float* outp = (float*)d_out;

    char* w = (char*)d_ws;
    int* deg = (int*)w;      w += (size_t)NNODES * sizeof(int);
    int* nbr = (int*)w;      w += (size_t)NNODES * MAXD * sizeof(int);
    ushort* hbuf = (ushort*)w; w += (size_t)4 * NNODES * 256 * sizeof(ushort); // 8 MB bf16
    float* esp = (float*)w;  w += (size_t)2 * PSTR * sizeof(float);
    float* edp = (float*)w;  w += (size_t)2 * PSTR * sizeof(float);
    ushort* Xhi = (ushort*)w; w += (size_t)NNODES * 1024 * sizeof(ushort);   // shared for x/x1/x2
    ushort* W1h = (ushort*)w; w += (size_t)4 * 256 * 64 * sizeof(ushort);
    ushort* W2h = (ushort*)w; w += (size_t)4 * 256 * 1024 * sizeof(ushort);
    ushort* W3h = (ushort*)w; w += (size_t)6 * 128 * 1024 * sizeof(ushort);
    float* agg = (float*)w;  w += (size_t)6 * NNODES * 128 * sizeof(float);  // 12.6 MB

    // LDS: tiles 64 KB (2 buf x 32 KB); es/ed epilogue needs 69632 B -> 72 KB
    constexpr size_t GEMM_LDS = 73728;

    // ---- fused CSR + weight/x prep (4096 + 2880 blocks)
    pre_kern<<<6976, 256, 0, stream>>>(adj, deg, nbr, x, W1, W2, W3,
                                       Xhi, W1h, W2h, W3h);

    // ---- Layer 1: x[4096,50] -> x1 (bf16 in Xhi)
    gemm_mfma<<<256, 256, GEMM_LDS, stream>>>(Xhi, W1h, hbuf,
                                              a1s, a1d, esp, edp, 64, 256, 256, 256, 2);
    aggregate_kern<4, 2, false><<<4 * NNODES / 4, 256, 0, stream>>>(
        hbuf, esp, edp, deg, nbr, Xhi);

    // ---- Layer 2: x1 -> x2 = ELU(gat(x1)) + x1 (residual from bf16 x1)
    gemm_mfma<<<256, 256, GEMM_LDS, stream>>>(Xhi, W2h, hbuf,
                                              a2s, a2d, esp, edp, 1024, 256, 256, 256, 2);
    aggregate_kern<4, 2, true><<<4 * NNODES / 4, 256, 0, stream>>>(
        hbuf, esp, edp, deg, nbr, Xhi);

    // ---- Layer 3: x2 -> out = log_softmax(mean_h gat(x2)); Hb bf16 stride 128
    gemm_mfma<<<192, 256, GEMM_LDS, stream>>>(Xhi, W3h, hbuf,
                                              a3s, a3d, esp, edp, 1024, 128, 128, 121, 1);
    aggregate3a_kern<<<6 * NNODES / 4, 256, 0, stream>>>(hbuf, esp, edp, deg, nbr, agg);
    reduce3_kern<<<NNODES / 4, 256, 0, stream>>>(agg, outp);
}

// Round 14
// 119.697 us; speedup vs baseline: 1.0307x; 1.0170x over previous
//
#include <hip/hip_runtime.h>
#include <hip/hip_bf16.h>
#include <math.h>

#define NNODES 4096
#define MAXD 128
#define PSTR (6 * NNODES)   // part stride for es/ed partials

typedef __attribute__((ext_vector_type(8))) short bf16x8;
typedef __attribute__((ext_vector_type(4))) float f32x4;
typedef __attribute__((ext_vector_type(2))) float f32x2;
typedef __attribute__((ext_vector_type(16))) float f32x16;
typedef __attribute__((ext_vector_type(4))) ushort u16x4;

__device__ inline ushort f32_to_bf16_rne(float f) {
    uint32_t u = __float_as_uint(f);
    u += 0x7FFFu + ((u >> 16) & 1u);
    return (ushort)(u >> 16);
}
__device__ inline float bf16_to_f32(ushort h) {
    return __uint_as_float((uint32_t)h << 16);
}
__device__ inline f32x4 u4_to_f32(u16x4 v) {
    f32x4 r;
    r[0] = bf16_to_f32(v[0]); r[1] = bf16_to_f32(v[1]);
    r[2] = bf16_to_f32(v[2]); r[3] = bf16_to_f32(v[3]);
    return r;
}

// ---------------------------------------------------------------------------
// Fused prologue: [0,4096) CSR build; [4096,6976) weight transpose + x split.
// ---------------------------------------------------------------------------
__global__ __launch_bounds__(256) void pre_kern(const int* __restrict__ adj,
                                                int* __restrict__ deg,
                                                int* __restrict__ nbr,
                                                const float* __restrict__ x,
                                                const float* __restrict__ W1,
                                                const float* __restrict__ W2,
                                                const float* __restrict__ W3,
                                                ushort* __restrict__ Xhi,
                                                ushort* __restrict__ W1h,
                                                ushort* __restrict__ W2h,
                                                ushort* __restrict__ W3h) {
    __shared__ float tile[32][33];
    __shared__ int cnts[256];
    int id = blockIdx.x;
    int tid = threadIdx.x;
    if (id < 4096) {
        int n = id;
        const int* row = adj + (size_t)n * NNODES;
        int c0 = tid * 16;
        int vals[16];
        const int4* r4 = (const int4*)(row + c0);
#pragma unroll
        for (int i = 0; i < 4; i++) {
            int4 v = r4[i];
            vals[4 * i] = v.x; vals[4 * i + 1] = v.y; vals[4 * i + 2] = v.z; vals[4 * i + 3] = v.w;
        }
        int cnt = 0;
#pragma unroll
        for (int i = 0; i < 16; i++) cnt += (vals[i] != 0) ? 1 : 0;
        cnts[tid] = cnt;
        __syncthreads();
        if (tid == 0) {
            int s = 0;
            for (int i = 0; i < 256; i++) { int c = cnts[i]; cnts[i] = s; s += c; }
            deg[n] = (s < MAXD) ? s : MAXD;
        }
        __syncthreads();
        int o = cnts[tid];
        int* outr = nbr + (size_t)n * MAXD;
#pragma unroll
        for (int i = 0; i < 16; i++) {
            if (vals[i] != 0) {
                if (o < MAXD) outr[o] = c0 + i;
                o++;
            }
        }
        return;
    }
    id -= 4096;
    if (id >= 1856) {
        int i = (id - 1856) * 256 + tid;
        int k = i & 63;
        int m = i >> 6;
        float v = (k < 50) ? x[(size_t)m * 50 + k] : 0.f;
        Xhi[i] = f32_to_bf16_rne(v);
        return;
    }
    const float* W; ushort* Whi;
    int h, r, K, KP, N, NP, gy;
    if (id < 64)        { W = W1; Whi = W1h; K = 50;   KP = 64;   N = 256; NP = 256; h = id / 16;           r = id % 16;         gy = 8; }
    else if (id < 1088) { W = W2; Whi = W2h; K = 1024; KP = 1024; N = 256; NP = 256; h = (id - 64) / 256;   r = (id - 64) % 256; gy = 8; }
    else                { W = W3; Whi = W3h; K = 1024; KP = 1024; N = 121; NP = 128; h = (id - 1088) / 128; r = (id - 1088) % 128; gy = 4; }
    int k0 = (r / gy) * 32, n0 = (r % gy) * 32;
    const float* Wh_ = W + (size_t)h * K * N;
#pragma unroll
    for (int q = 0; q < 4; q++) {
        int kl = (tid >> 5) + q * 8;
        int nl = tid & 31;
        int k = k0 + kl, n = n0 + nl;
        tile[kl][nl] = (k < K && n < N) ? Wh_[(size_t)k * N + n] : 0.f;
    }
    __syncthreads();
#pragma unroll
    for (int q = 0; q < 4; q++) {
        int nl = (tid >> 5) + q * 8;
        int kl = tid & 31;
        size_t o = ((size_t)h * NP + n0 + nl) * KP + k0 + kl;
        Whi[o] = f32_to_bf16_rne(tile[kl][nl]);
    }
}

// ---------------------------------------------------------------------------
// bf16 MFMA GEMM, XCD-pinned by head. Block tile 64x128 (4 waves 2x2),
// wave tile 32x64 = 1x2 frags of 32x32x16. BK=64, 2 blocks/CU (48 KB LDS)
// -> 2 waves/SIMD so MFMA of one wave hides ds_read/stage of the other.
// Staging: global_load_lds width=16, double-buffered, issue-before-compute,
// one barrier per K-step. Linear LDS + source-side chunk swizzle lc=pc^(row&7);
// frag b128 reads apply the same involution -> conflict-free.
// C written bf16; fused es/ed per-block partials from fp32 accumulators.
// ---------------------------------------------------------------------------
__global__ __launch_bounds__(256, 2) void gemm_mfma(const ushort* __restrict__ Xhi,
                                                    const ushort* __restrict__ Whi,
                                                    ushort* __restrict__ Hb,
                                                    const float* __restrict__ AsrcAll,
                                                    const float* __restrict__ AdstAll,
                                                    float* __restrict__ esp,
                                                    float* __restrict__ edp,
                                                    int KP, int NP, int Nstride, int Nreal,
                                                    int nby) {
    extern __shared__ ushort lds[];
    constexpr int AH = 0, BH = 4096, BUF = 12288;   // ushort idx; A 64x64, B 128x64
    int b = blockIdx.x;
    int perx = gridDim.x >> 3;
    int g = (b & 7) * perx + (b >> 3);
    int per_head = 64 * nby;                        // 64 m-blocks of 64 rows
    int h = g / per_head;
    int r0 = g - h * per_head;
    const int m0 = (r0 / nby) * 64;
    const int n0 = (r0 % nby) * 128;
    const int blkj = n0 >> 7;
    const int tid = threadIdx.x;
    const int lane = tid & 63;
    const int w = tid >> 6;
    const int wr = (w >> 1) * 32, wc = (w & 1) * 64;
    const int fr = lane & 31;
    const int fg = lane >> 5;
    const ushort* Wh_ = Whi + (size_t)h * NP * KP;
    auto STAGE = [&](int buf, int K0) {
#pragma unroll
        for (int i = 0; i < 2; i++) {               // A: 512 chunks of 16 B
            int c = w * 64 + i * 256 + lane;
            int row = c >> 3;
            int lc = (c & 7) ^ (row & 7);
            const ushort* ga = &Xhi[(size_t)(m0 + row) * KP + K0 + lc * 8];
            ushort* la = &lds[buf * BUF + AH + (w * 64 + i * 256) * 8];
            __builtin_amdgcn_global_load_lds(
                (const __attribute__((address_space(1))) uint32_t*)ga,
                (__attribute__((address_space(3))) uint32_t*)la, 16, 0, 0);
        }
#pragma unroll
        for (int i = 0; i < 4; i++) {               // B: 1024 chunks
            int c = w * 64 + i * 256 + lane;
            int row = c >> 3;
            int lc = (c & 7) ^ (row & 7);
            const ushort* gb = &Wh_[(size_t)(n0 + row) * KP + K0 + lc * 8];
            ushort* lb = &lds[buf * BUF + BH + (w * 64 + i * 256) * 8];
            __builtin_amdgcn_global_load_lds(
                (const __attribute__((address_space(1))) uint32_t*)gb,
                (__attribute__((address_space(3))) uint32_t*)lb, 16, 0, 0);
        }
    };
    STAGE(0, 0);
    __syncthreads();
    f32x16 acc[2] = {};
    int cur = 0;
    for (int k0 = 0; k0 < KP; k0 += 64) {
        if (k0 + 64 < KP) STAGE(cur ^ 1, k0 + 64);  // async, drains at next barrier
        const int bo = cur * BUF;
#pragma unroll
        for (int ks = 0; ks < 4; ks++) {
            const int pc = (ks * 2 + fg) ^ (fr & 7);
            bf16x8 a  = *(const bf16x8*)&lds[bo + AH + (wr + fr) * 64 + pc * 8];
            bf16x8 b0 = *(const bf16x8*)&lds[bo + BH + (wc + fr) * 64 + pc * 8];
            bf16x8 b1 = *(const bf16x8*)&lds[bo + BH + (wc + 32 + fr) * 64 + pc * 8];
            acc[0] = __builtin_amdgcn_mfma_f32_32x32x16_bf16(a, b0, acc[0], 0, 0, 0);
            acc[1] = __builtin_amdgcn_mfma_f32_32x32x16_bf16(a, b1, acc[1], 0, 0, 0);
        }
        __syncthreads();
        cur ^= 1;
    }
    // C write (bf16): 32x32 layout col=lane&31, row=(reg&3)+8*(reg>>2)+4*(lane>>5)
#pragma unroll
    for (int j = 0; j < 2; j++)
#pragma unroll
        for (int reg = 0; reg < 16; reg++) {
            int row = m0 + wr + (reg & 3) + 8 * (reg >> 2) + 4 * fg;
            int col = n0 + wc + j * 32 + fr;
            Hb[((size_t)h * NNODES + row) * Nstride + col] = f32_to_bf16_rne(acc[j][reg]);
        }
    // ---- fused es/ed partials (fp32-exact from accumulators) ----
    __syncthreads();
    float* fl = (float*)lds;               // [2 wcidx][64][34] es, then ed (34816 B)
    constexpr int EDO = 2 * 64 * 34;
    const float* Asrc = AsrcAll + (size_t)h * Nreal;
    const float* Adst = AdstAll + (size_t)h * Nreal;
    float as_[2], ad_[2];
#pragma unroll
    for (int j = 0; j < 2; j++) {
        int col = n0 + wc + j * 32 + fr;
        as_[j] = (col < Nreal) ? Asrc[col] : 0.f;
        ad_[j] = (col < Nreal) ? Adst[col] : 0.f;
    }
    const int wcidx = (w & 1);
#pragma unroll
    for (int reg = 0; reg < 16; reg++) {
        int row = wr + (reg & 3) + 8 * (reg >> 2) + 4 * fg;     // 0..63
        float pe = acc[0][reg] * as_[0] + acc[1][reg] * as_[1];
        float pd = acc[0][reg] * ad_[0] + acc[1][reg] * ad_[1];
        fl[(wcidx * 64 + row) * 34 + fr] = pe;
        fl[EDO + (wcidx * 64 + row) * 34 + fr] = pd;
    }
    __syncthreads();
    if (tid < 64) {
        int r = tid;
        float s = 0.f;
#pragma unroll
        for (int q = 0; q < 32; q++)
            s += fl[r * 34 + q] + fl[(64 + r) * 34 + q];
        esp[(size_t)blkj * PSTR + h * NNODES + m0 + r] = s;
    } else if (tid < 128) {
        int r = tid - 64;
        float s = 0.f;
#pragma unroll
        for (int q = 0; q < 32; q++)
            s += fl[EDO + r * 34 + q] + fl[EDO + (64 + r) * 34 + q];
        edp[(size_t)blkj * PSTR + h * NNODES + m0 + r] = s;
    }
}

// ---------------------------------------------------------------------------
// Sparse masked-softmax attention aggregate, layers 1/2 (FOUT=256, bf16 Hb).
// XCD-pinned by head. 4-way unrolled gathers, 4 independent accumulators.
// ---------------------------------------------------------------------------
template<int HEADS, int NPARTS, bool RES>
__global__ __launch_bounds__(256) void aggregate_kern(const ushort* __restrict__ Hb,
                                                      const float* __restrict__ esp,
                                                      const float* __restrict__ edp,
                                                      const int* __restrict__ deg,
                                                      const int* __restrict__ nbr,
                                                      ushort* outHi) {
    constexpr int FOUT = 256;
    int b = blockIdx.x;
    int g = (b & 7) * ((HEADS * NNODES / 4) / 8) + (b >> 3);
    int h = g / (NNODES / 4);
    int n = (g % (NNODES / 4)) * 4 + (threadIdx.x >> 6);
    int lane = threadIdx.x & 63;
    int d = deg[n];
    const int* nb = nbr + (size_t)n * MAXD;
    float esn = esp[h * NNODES + n];
    if (NPARTS == 2) esn += esp[PSTR + h * NNODES + n];
    float sc[2];
    int nm[2];
    float mx = -INFINITY;
#pragma unroll
    for (int r = 0; r < 2; r++) {
        int j = lane + r * 64;
        int m = (j < d) ? nb[j] : 0;
        nm[r] = m;
        float e = -INFINITY;
        if (j < d) {
            float t = esn + edp[h * NNODES + m];
            if (NPARTS == 2) t += edp[PSTR + h * NNODES + m];
            e = (t > 0.f) ? t : 0.2f * t;
        }
        sc[r] = e;
        mx = fmaxf(mx, e);
    }
#pragma unroll
    for (int sh = 32; sh >= 1; sh >>= 1) mx = fmaxf(mx, __shfl_xor(mx, sh));
    float sum = 0.f;
#pragma unroll
    for (int r = 0; r < 2; r++) {
        float ex = (sc[r] == -INFINITY) ? 0.f : expf(sc[r] - mx);
        sc[r] = ex;
        sum += ex;
    }
#pragma unroll
    for (int sh = 32; sh >= 1; sh >>= 1) sum += __shfl_xor(sum, sh);
    float inv = 1.f / sum;
    sc[0] *= inv; sc[1] *= inv;
    const ushort* Hh = Hb + (size_t)h * NNODES * FOUT;
    f32x4 ac0 = {}, ac1 = {}, ac2 = {}, ac3 = {};
    int j = 0;
    for (; j + 3 < d; j += 4) {
        float a0 = __shfl(sc[j >> 6], j & 63);
        int q0 = __shfl(nm[j >> 6], j & 63);
        float a1 = __shfl(sc[(j + 1) >> 6], (j + 1) & 63);
        int q1 = __shfl(nm[(j + 1) >> 6], (j + 1) & 63);
        float a2 = __shfl(sc[(j + 2) >> 6], (j + 2) & 63);
        int q2 = __shfl(nm[(j + 2) >> 6], (j + 2) & 63);
        float a3 = __shfl(sc[(j + 3) >> 6], (j + 3) & 63);
        int q3 = __shfl(nm[(j + 3) >> 6], (j + 3) & 63);
        u16x4 v0 = *(const u16x4*)&Hh[(size_t)q0 * FOUT + lane * 4];
        u16x4 v1 = *(const u16x4*)&Hh[(size_t)q1 * FOUT + lane * 4];
        u16x4 v2 = *(const u16x4*)&Hh[(size_t)q2 * FOUT + lane * 4];
        u16x4 v3 = *(const u16x4*)&Hh[(size_t)q3 * FOUT + lane * 4];
        ac0 += a0 * u4_to_f32(v0);
        ac1 += a1 * u4_to_f32(v1);
        ac2 += a2 * u4_to_f32(v2);
        ac3 += a3 * u4_to_f32(v3);
    }
    for (; j < d; j++) {
        float a0 = __shfl(sc[j >> 6], j & 63);
        int q0 = __shfl(nm[j >> 6], j & 63);
        u16x4 v0 = *(const u16x4*)&Hh[(size_t)q0 * FOUT + lane * 4];
        ac0 += a0 * u4_to_f32(v0);
    }
    f32x4 acc = (ac0 + ac1) + (ac2 + ac3);
    size_t idx = (size_t)n * (HEADS * FOUT) + (size_t)h * FOUT + lane * 4;
    u16x4 hi4, rh;
    if (RES) rh = *(const u16x4*)&outHi[idx];
#pragma unroll
    for (int i = 0; i < 4; i++) {
        float v = acc[i];
        v = (v > 0.f) ? v : (expf(v) - 1.f);
        if (RES) v += bf16_to_f32(rh[i]);
        hi4[i] = f32_to_bf16_rne(v);
    }
    *(u16x4*)&outHi[idx] = hi4;
}

// ---------------------------------------------------------------------------
// Layer 3a: per-(h,n) pinned aggregate -> agg[h][n][128] (fp32, stride 128).
// ---------------------------------------------------------------------------
__global__ __launch_bounds__(256) void aggregate3a_kern(const ushort* __restrict__ Hb,
                                                        const float* __restrict__ esp,
                                                        const float* __restrict__ edp,
                                                        const int* __restrict__ deg,
                                                        const int* __restrict__ nbr,
                                                        float* __restrict__ agg) {
    constexpr int HEADS = 6;
    int b = blockIdx.x;
    int g = (b & 7) * ((HEADS * NNODES / 4) / 8) + (b >> 3);
    int h = g / (NNODES / 4);
    int n = (g % (NNODES / 4)) * 4 + (threadIdx.x >> 6);
    int lane = threadIdx.x & 63;
    int d = deg[n];
    const int* nb = nbr + (size_t)n * MAXD;
    float esn = esp[h * NNODES + n];
    float sc[2];
    int nm[2];
    float mx = -INFINITY;
#pragma unroll
    for (int r = 0; r < 2; r++) {
        int j = lane + r * 64;
        int m = (j < d) ? nb[j] : 0;
        nm[r] = m;
        float e = -INFINITY;
        if (j < d) {
            float t = esn + edp[h * NNODES + m];
            e = (t > 0.f) ? t : 0.2f * t;
        }
        sc[r] = e;
        mx = fmaxf(mx, e);
    }
#pragma unroll
    for (int sh = 32; sh >= 1; sh >>= 1) mx = fmaxf(mx, __shfl_xor(mx, sh));
    float sum = 0.f;
#pragma unroll
    for (int r = 0; r < 2; r++) {
        float ex = (sc[r] == -INFINITY) ? 0.f : expf(sc[r] - mx);
        sc[r] = ex;
        sum += ex;
    }
#pragma unroll
    for (int sh = 32; sh >= 1; sh >>= 1) sum += __shfl_xor(sum, sh);
    float inv = 1.f / sum;
    sc[0] *= inv; sc[1] *= inv;
    const ushort* Hh = Hb + (size_t)h * NNODES * 128;
    int c0 = lane * 2;
    f32x2 ac0 = {}, ac1 = {}, ac2 = {}, ac3 = {};
    auto LD = [&](int q) -> f32x2 {
        uint vv = *(const uint*)&Hh[(size_t)q * 128 + c0];
        f32x2 r;
        r[0] = bf16_to_f32((ushort)(vv & 0xffffu));
        r[1] = bf16_to_f32((ushort)(vv >> 16));
        return r;
    };
    int j = 0;
    for (; j + 3 < d; j += 4) {
        float a0 = __shfl(sc[j >> 6], j & 63);
        int q0 = __shfl(nm[j >> 6], j & 63);
        float a1 = __shfl(sc[(j + 1) >> 6], (j + 1) & 63);
        int q1 = __shfl(nm[(j + 1) >> 6], (j + 1) & 63);
        float a2 = __shfl(sc[(j + 2) >> 6], (j + 2) & 63);
        int q2 = __shfl(nm[(j + 2) >> 6], (j + 2) & 63);
        float a3 = __shfl(sc[(j + 3) >> 6], (j + 3) & 63);
        int q3 = __shfl(nm[(j + 3) >> 6], (j + 3) & 63);
        ac0 += a0 * LD(q0);
        ac1 += a1 * LD(q1);
        ac2 += a2 * LD(q2);
        ac3 += a3 * LD(q3);
    }
    for (; j < d; j++) {
        float a0 = __shfl(sc[j >> 6], j & 63);
        int q0 = __shfl(nm[j >> 6], j & 63);
        ac0 += a0 * LD(q0);
    }
    f32x2 acc = (ac0 + ac1) + (ac2 + ac3);
    *(f32x2*)&agg[((size_t)h * NNODES + n) * 128 + c0] = acc;
}

// ---------------------------------------------------------------------------
// Layer 3b: mean over 6 heads + row log_softmax (121 classes). 1 wave/node.
// ---------------------------------------------------------------------------
__global__ __launch_bounds__(256) void reduce3_kern(const float* __restrict__ agg,
                                                    float* __restrict__ outp) {
    constexpr int FOUT = 121;
    int n = blockIdx.x * 4 + (threadIdx.x >> 6);
    int lane = threadIdx.x & 63;
    int c0 = lane * 2;
    f32x2 l = {};
#pragma unroll
    for (int h = 0; h < 6; h++)
        l += *(const f32x2*)&agg[((size_t)h * NNODES + n) * 128 + c0];
    l = l * (1.f / 6.f);
    float m0 = (c0 < FOUT) ? l[0] : -INFINITY;
    float m1 = (c0 + 1 < FOUT) ? l[1] : -INFINITY;
    float mx = fmaxf(m0, m1);
#pragma unroll
    for (int sh = 32; sh >= 1; sh >>= 1) mx = fmaxf(mx, __shfl_xor(mx, sh));
    float s = ((c0 < FOUT) ? expf(l[0] - mx) : 0.f) + ((c0 + 1 < FOUT) ? expf(l[1] - mx) : 0.f);
#pragma unroll
    for (int sh = 32; sh >= 1; sh >>= 1) s += __shfl_xor(s, sh);
    float lse = logf(s);
    if (c0 < FOUT) outp[(size_t)n * FOUT + c0] = l[0] - mx - lse;
    if (c0 + 1 < FOUT) outp[(size_t)n * FOUT + c0 + 1] = l[1] - mx - lse;
}

// ---------------------------------------------------------------------------
extern "C" void kernel_launch(void* const* d_in, const int* in_sizes, int n_in,
                              void* d_out, int out_size, void* d_ws, size_t ws_size,
                              hipStream_t stream) {
    const float* x   = (const float*)d_in[0];
    const int*   adj = (const int*)d_in[1];
    const float* W1  = (const float*)d_in[2];
    const float* a1s = (const float*)d_in[3];
    const float* a1d = (const float*)d_in[4];
    const float* W2  = (const float*)d_in[5];
    const float* a2s = (const float*)d_in[6];
    const float* a2d = (const float*)d_in[7];
    const float* W3  = (const float*)d_in[8];
    const float* a3s = (const float*)d_in[9];
    const float* a3d = (const float*)d_in[10];
    float* outp = (float*)d_out;

    char* w = (char*)d_ws;
    int* deg = (int*)w;      w += (size_t)NNODES * sizeof(int);
    int* nbr = (int*)w;      w += (size_t)NNODES * MAXD * sizeof(int);
    ushort* hbuf = (ushort*)w; w += (size_t)4 * NNODES * 256 * sizeof(ushort); // 8 MB bf16
    float* esp = (float*)w;  w += (size_t)2 * PSTR * sizeof(float);
    float* edp = (float*)w;  w += (size_t)2 * PSTR * sizeof(float);
    ushort* Xhi = (ushort*)w; w += (size_t)NNODES * 1024 * sizeof(ushort);   // shared for x/x1/x2
    ushort* W1h = (ushort*)w; w += (size_t)4 * 256 * 64 * sizeof(ushort);
    ushort* W2h = (ushort*)w; w += (size_t)4 * 256 * 1024 * sizeof(ushort);
    ushort* W3h = (ushort*)w; w += (size_t)6 * 128 * 1024 * sizeof(ushort);
    float* agg = (float*)w;  w += (size_t)6 * NNODES * 128 * sizeof(float);  // 12.6 MB

    // LDS: tiles 48 KB (2 buf x 24 KB); es/ed epilogue 34816 B fits inside
    constexpr size_t GEMM_LDS = 49152;

    // ---- fused CSR + weight/x prep (4096 + 2880 blocks)
    pre_kern<<<6976, 256, 0, stream>>>(adj, deg, nbr, x, W1, W2, W3,
                                       Xhi, W1h, W2h, W3h);

    // ---- Layer 1: x[4096,50] -> x1 (bf16 in Xhi)
    gemm_mfma<<<512, 256, GEMM_LDS, stream>>>(Xhi, W1h, hbuf,
                                              a1s, a1d, esp, edp, 64, 256, 256, 256, 2);
    aggregate_kern<4, 2, false><<<4 * NNODES / 4, 256, 0, stream>>>(
        hbuf, esp, edp, deg, nbr, Xhi);

    // ---- Layer 2: x1 -> x2 = ELU(gat(x1)) + x1 (residual from bf16 x1)
    gemm_mfma<<<512, 256, GEMM_LDS, stream>>>(Xhi, W2h, hbuf,
                                              a2s, a2d, esp, edp, 1024, 256, 256, 256, 2);
    aggregate_kern<4, 2, true><<<4 * NNODES / 4, 256, 0, stream>>>(
        hbuf, esp, edp, deg, nbr, Xhi);

    // ---- Layer 3: x2 -> out = log_softmax(mean_h gat(x2)); Hb bf16 stride 128
    gemm_mfma<<<384, 256, GEMM_LDS, stream>>>(Xhi, W3h, hbuf,
                                              a3s, a3d, esp, edp, 1024, 128, 128, 121, 1);
    aggregate3a_kern<<<6 * NNODES / 4, 256, 0, stream>>>(hbuf, esp, edp, deg, nbr, agg);
    reduce3_kern<<<NNODES / 4, 256, 0, stream>>>(agg, outp);
}